// Round 5
// baseline (265.457 us; speedup 1.0000x reference)
//
#include <hip/hip_runtime.h>

// Problem constants (fixed by the reference)
constexpr int L    = 8192;   // vector_length
constexpr int B    = 4096;   // batch (columns)
constexpr int RANK = 8;

// Pass-1 tiling: 32 l-chunks of 256 rows x 16 col-stripes of 256 cols
//   = 512 blocks (2/CU). Each of the 4 waves covers a disjoint 64-row
//   group; an LDS fold merges them so only ONE partial per chunk hits HBM.
//   The 32nd (last) block to finish a stripe reduces its 32 chunks -> T,
//   eliminating the separate reduce dispatch + launch gap.
constexpr int NCHUNK  = 32;
constexpr int ROWS_PC = L / NCHUNK;     // 256 rows per chunk
constexpr int CSTRIPE = 16;             // col stripes
constexpr int COLS_PS = B / CSTRIPE;    // 256 cols per stripe (64 lanes x float4)
constexpr int UNROLL  = 8;

// Pass-2 tiling
constexpr int CB      = 4;
constexpr int COLS_PB = 1024;
constexpr int LPB     = 32;             // l-rows per block -> 1024 blocks = 4/CU

// Native vector type acceptable to __builtin_nontemporal_{load,store}
typedef float nfloat4 __attribute__((ext_vector_type(4)));

// Per-stripe arrival counters. Module-scope .bss: zeroed at module load,
// NOT part of d_ws so the harness poison fills never touch it. Each launch
// adds exactly 32 per stripe, so "last arrival" == ((old & 31) == 31) holds
// for every timed iteration and every rocprof replay without re-zeroing.
__device__ unsigned int g_cnt[CSTRIPE];

// ---------------------------------------------------------------------------
// pass1: part[lc][r][b] = sum_{l in chunk lc} V[r][l] * in[l][b]
//        + last-block-per-stripe reduction: T[r][b] = sum_lc part[lc][r][b]
// ---------------------------------------------------------------------------
__global__ __launch_bounds__(256) void lr_pass1(const float* __restrict__ in,
                                                const float* __restrict__ V,
                                                float* __restrict__ part,
                                                float* __restrict__ T) {
    const int cs   = blockIdx.x % CSTRIPE;
    const int lc   = blockIdx.x / CSTRIPE;
    const int tid  = threadIdx.x;
    const int lane = tid & 63;
    const int w    = tid >> 6;                  // wave 0..3
    const int col  = cs * COLS_PS + lane * 4;
    const int l0   = lc * ROWS_PC;

    __shared__ float  vs[RANK][ROWS_PC];        // 8 KiB: V slice for the chunk
    __shared__ float4 fold[3][64][RANK];        // 24 KiB: waves 1-3 partials
    __shared__ int    isLast;

    for (int i = tid; i < RANK * ROWS_PC; i += 256) {
        const int r  = i / ROWS_PC;
        const int ll = i % ROWS_PC;
        vs[r][ll] = V[r * L + l0 + ll];
    }
    __syncthreads();

    float4 acc[RANK];
#pragma unroll
    for (int r = 0; r < RANK; ++r) acc[r] = make_float4(0.f, 0.f, 0.f, 0.f);

    const float* base = in + (size_t)(l0 + w * 64) * B + col;
    for (int li = 0; li < 64; li += UNROLL) {
        float4 x[UNROLL];
#pragma unroll
        for (int j = 0; j < UNROLL; ++j)
            x[j] = *(const float4*)(base + (size_t)(li + j) * B);
#pragma unroll
        for (int j = 0; j < UNROLL; ++j) {
#pragma unroll
            for (int r = 0; r < RANK; ++r) {
                const float v = vs[r][w * 64 + li + j];
                acc[r].x += v * x[j].x;
                acc[r].y += v * x[j].y;
                acc[r].z += v * x[j].z;
                acc[r].w += v * x[j].w;
            }
        }
    }

    if (w > 0) {
#pragma unroll
        for (int r = 0; r < RANK; ++r) fold[w - 1][lane][r] = acc[r];
    }
    __syncthreads();

    if (w == 0) {
        float* p = part + (size_t)lc * (RANK * B);
#pragma unroll
        for (int r = 0; r < RANK; ++r) {
            const float4 a = fold[0][lane][r];
            const float4 b = fold[1][lane][r];
            const float4 c = fold[2][lane][r];
            float4 o;
            o.x = acc[r].x + ((a.x + b.x) + c.x);
            o.y = acc[r].y + ((a.y + b.y) + c.y);
            o.z = acc[r].z + ((a.z + b.z) + c.z);
            o.w = acc[r].w + ((a.w + b.w) + c.w);
            *(float4*)(p + r * B + col) = o;
        }
        // release: each storing thread fences its own part stores
        __threadfence();
    }
    __syncthreads();

    if (tid == 0) {
        const unsigned old = atomicAdd(&g_cnt[cs], 1u);
        isLast = ((old & 31u) == 31u);
        if (isLast) __threadfence();   // acquire side
    }
    __syncthreads();

    if (isLast) {
        // Reduce stripe cs: 8 ranks x 64 float4 = 512 float4; 2 per thread.
#pragma unroll
        for (int idx = tid; idx < RANK * (COLS_PS / 4); idx += 256) {
            const int r    = idx >> 6;          // 0..7
            const int c4   = idx & 63;          // float4 within stripe
            const float* p = part + (size_t)r * B + cs * COLS_PS + c4 * 4;
            float4 s = make_float4(0.f, 0.f, 0.f, 0.f);
#pragma unroll 8
            for (int c = 0; c < NCHUNK; ++c) {
                const float4 v = *(const float4*)(p + (size_t)c * (RANK * B));
                s.x += v.x; s.y += v.y; s.z += v.z; s.w += v.w;
            }
            *(float4*)(T + r * B + cs * COLS_PS + c4 * 4) = s;
        }
    }
}

// ---------------------------------------------------------------------------
// pass2: out[l][b] = sum_r U[r][l] * T[r][b]
// out stores nontemporal: never re-read, keep L2 for in/T.
// ---------------------------------------------------------------------------
__global__ __launch_bounds__(256) void lr_pass2(const float* __restrict__ T,
                                                const float* __restrict__ U,
                                                float* __restrict__ out) {
    const int cb  = blockIdx.x % CB;
    const int lb  = blockIdx.x / CB;
    const int col = cb * COLS_PB + threadIdx.x * 4;
    const int l0  = lb * LPB;

    __shared__ float us[RANK][LPB];     // 1 KiB
    if (threadIdx.x < RANK * LPB) {
        const int r  = threadIdx.x / LPB;
        const int ll = threadIdx.x % LPB;
        us[r][ll] = U[r * L + l0 + ll];
    }
    __syncthreads();

    float4 t[RANK];
#pragma unroll
    for (int r = 0; r < RANK; ++r) t[r] = *(const float4*)(T + r * B + col);

#pragma unroll
    for (int li = 0; li < LPB; ++li) {
        nfloat4 o = {0.f, 0.f, 0.f, 0.f};
#pragma unroll
        for (int r = 0; r < RANK; ++r) {
            const float u = us[r][li];
            o.x += u * t[r].x;
            o.y += u * t[r].y;
            o.z += u * t[r].z;
            o.w += u * t[r].w;
        }
        __builtin_nontemporal_store(o, (nfloat4*)(out + (size_t)(l0 + li) * B + col));
    }
}

// ---------------------------------------------------------------------------
extern "C" void kernel_launch(void* const* d_in, const int* in_sizes, int n_in,
                              void* d_out, int out_size, void* d_ws, size_t ws_size,
                              hipStream_t stream) {
    const float* in = (const float*)d_in[0];   // [L, B]
    const float* U  = (const float*)d_in[1];   // [RANK, L]
    const float* V  = (const float*)d_in[2];   // [RANK, L]
    float* out = (float*)d_out;                // [L, B]

    // ws layout: partials (NCHUNK * RANK * B floats = 4 MiB) then T (RANK*B)
    float* part = (float*)d_ws;
    float* T    = part + (size_t)NCHUNK * RANK * B;

    lr_pass1<<<CSTRIPE * NCHUNK, 256, 0, stream>>>(in, V, part, T);
    lr_pass2<<<CB * (L / LPB),   256, 0, stream>>>(T, U, out);
}

// Round 6
// 242.285 us; speedup vs baseline: 1.0956x; 1.0956x over previous
//
#include <hip/hip_runtime.h>

// Problem constants (fixed by the reference)
constexpr int L    = 8192;   // vector_length
constexpr int B    = 4096;   // batch (columns)
constexpr int RANK = 8;

// Pass-1 tiling: 32 l-chunks of 256 rows x 16 col-stripes of 256 cols
//   = 512 blocks (2/CU). Each of the 4 waves covers a disjoint 64-row
//   group; an LDS fold merges them so only ONE partial per chunk hits HBM
//   (part = 4.2 MB). Fold layout is [w][r][lane] so float4 accesses are
//   lane-contiguous (conflict-free); [w][lane][r] was a 16-way conflict
//   (1.03M conflict cycles measured in round 5's profile).
constexpr int NCHUNK  = 32;
constexpr int ROWS_PC = L / NCHUNK;     // 256 rows per chunk
constexpr int CSTRIPE = 16;             // col stripes
constexpr int COLS_PS = B / CSTRIPE;    // 256 cols per stripe (64 lanes x float4)
constexpr int UNROLL  = 8;

// Pass-2 tiling
constexpr int CB      = 4;
constexpr int COLS_PB = 1024;
constexpr int LPB     = 32;             // l-rows per block -> 1024 blocks = 4/CU

// Native vector type acceptable to __builtin_nontemporal_{load,store}
typedef float nfloat4 __attribute__((ext_vector_type(4)));

// ---------------------------------------------------------------------------
// pass1: part[lc][r][b] = sum_{l in chunk lc} V[r][l] * in[l][b]
// wave w handles rows [lc*256 + w*64, +64); LDS fold merges 4 waves.
// NOTE: no cross-block sync here — both the cooperative-grid version
// (+150 us) and the threadfence/last-block version (+24 us) regressed;
// kernel boundaries are cheaper than any in-kernel global sync on MI355X.
// ---------------------------------------------------------------------------
__global__ __launch_bounds__(256) void lr_pass1(const float* __restrict__ in,
                                                const float* __restrict__ V,
                                                float* __restrict__ part) {
    const int cs   = blockIdx.x % CSTRIPE;
    const int lc   = blockIdx.x / CSTRIPE;
    const int tid  = threadIdx.x;
    const int lane = tid & 63;
    const int w    = tid >> 6;                  // wave 0..3
    const int col  = cs * COLS_PS + lane * 4;
    const int l0   = lc * ROWS_PC;

    __shared__ float  vs[RANK][ROWS_PC];        // 8 KiB: V slice for the chunk
    __shared__ float4 fold[3][RANK][64];        // 24 KiB: waves 1-3 partials

    for (int i = tid; i < RANK * ROWS_PC; i += 256) {
        const int r  = i / ROWS_PC;
        const int ll = i % ROWS_PC;
        vs[r][ll] = V[r * L + l0 + ll];
    }
    __syncthreads();

    float4 acc[RANK];
#pragma unroll
    for (int r = 0; r < RANK; ++r) acc[r] = make_float4(0.f, 0.f, 0.f, 0.f);

    const float* base = in + (size_t)(l0 + w * 64) * B + col;
    for (int li = 0; li < 64; li += UNROLL) {
        float4 x[UNROLL];
#pragma unroll
        for (int j = 0; j < UNROLL; ++j)
            x[j] = *(const float4*)(base + (size_t)(li + j) * B);
#pragma unroll
        for (int j = 0; j < UNROLL; ++j) {
#pragma unroll
            for (int r = 0; r < RANK; ++r) {
                const float v = vs[r][w * 64 + li + j];
                acc[r].x += v * x[j].x;
                acc[r].y += v * x[j].y;
                acc[r].z += v * x[j].z;
                acc[r].w += v * x[j].w;
            }
        }
    }

    if (w > 0) {
#pragma unroll
        for (int r = 0; r < RANK; ++r) fold[w - 1][r][lane] = acc[r];
    }
    __syncthreads();

    if (w == 0) {
        float* p = part + (size_t)lc * (RANK * B);
#pragma unroll
        for (int r = 0; r < RANK; ++r) {
            const float4 a = fold[0][r][lane];
            const float4 b = fold[1][r][lane];
            const float4 c = fold[2][r][lane];
            nfloat4 o;
            o.x = acc[r].x + ((a.x + b.x) + c.x);
            o.y = acc[r].y + ((a.y + b.y) + c.y);
            o.z = acc[r].z + ((a.z + b.z) + c.z);
            o.w = acc[r].w + ((a.w + b.w) + c.w);
            __builtin_nontemporal_store(o, (nfloat4*)(p + r * B + col));
        }
    }
}

// ---------------------------------------------------------------------------
// reduce: T[i] = sum_{c<32} part[c][i] — 512 blocks (2/CU), 16 float4 each.
// wave w sums chunks [w*8,(w+1)*8): lane = sub*16+e, sub sums 2 chunks;
// butterfly xor{16,32} folds subs; LDS folds the 4 waves.
// ---------------------------------------------------------------------------
__global__ __launch_bounds__(256) void lr_reduce(const float* __restrict__ part,
                                                 float* __restrict__ T) {
    const int tid  = threadIdx.x;
    const int bid  = blockIdx.x;
    const int lane = tid & 63;
    const int w    = tid >> 6;                 // wave 0..3
    const int e    = bid * 16 + (lane & 15);   // float4 index into T
    const int sub  = lane >> 4;                // 0..3
    const int c0   = w * 8 + sub * 2;
    const nfloat4* p4 = (const nfloat4*)part;

    __shared__ float4 red[4][16];

    nfloat4 s = {0.f, 0.f, 0.f, 0.f};
#pragma unroll
    for (int k = 0; k < 2; ++k) {
        const nfloat4 v =
            __builtin_nontemporal_load(&p4[(size_t)(c0 + k) * (RANK * B / 4) + e]);
        s += v;
    }
    float4 sv = make_float4(s.x, s.y, s.z, s.w);
#pragma unroll
    for (int m = 16; m < 64; m <<= 1) {
        sv.x += __shfl_xor(sv.x, m, 64);
        sv.y += __shfl_xor(sv.y, m, 64);
        sv.z += __shfl_xor(sv.z, m, 64);
        sv.w += __shfl_xor(sv.w, m, 64);
    }
    if (lane < 16) red[w][lane] = sv;
    __syncthreads();
    if (w == 0 && lane < 16) {
        const float4 a = red[0][lane];
        const float4 b = red[1][lane];
        const float4 c = red[2][lane];
        const float4 d = red[3][lane];
        float4 t;
        t.x = (a.x + b.x) + (c.x + d.x);
        t.y = (a.y + b.y) + (c.y + d.y);
        t.z = (a.z + b.z) + (c.z + d.z);
        t.w = (a.w + b.w) + (c.w + d.w);
        ((float4*)T)[bid * 16 + lane] = t;
    }
}

// ---------------------------------------------------------------------------
// pass2: out[l][b] = sum_r U[r][l] * T[r][b]
// out stores nontemporal: never re-read, keep L2 for in/T.
// ---------------------------------------------------------------------------
__global__ __launch_bounds__(256) void lr_pass2(const float* __restrict__ T,
                                                const float* __restrict__ U,
                                                float* __restrict__ out) {
    const int cb  = blockIdx.x % CB;
    const int lb  = blockIdx.x / CB;
    const int col = cb * COLS_PB + threadIdx.x * 4;
    const int l0  = lb * LPB;

    __shared__ float us[RANK][LPB];     // 1 KiB
    if (threadIdx.x < RANK * LPB) {
        const int r  = threadIdx.x / LPB;
        const int ll = threadIdx.x % LPB;
        us[r][ll] = U[r * L + l0 + ll];
    }
    __syncthreads();

    float4 t[RANK];
#pragma unroll
    for (int r = 0; r < RANK; ++r) t[r] = *(const float4*)(T + r * B + col);

#pragma unroll
    for (int li = 0; li < LPB; ++li) {
        nfloat4 o = {0.f, 0.f, 0.f, 0.f};
#pragma unroll
        for (int r = 0; r < RANK; ++r) {
            const float u = us[r][li];
            o.x += u * t[r].x;
            o.y += u * t[r].y;
            o.z += u * t[r].z;
            o.w += u * t[r].w;
        }
        __builtin_nontemporal_store(o, (nfloat4*)(out + (size_t)(l0 + li) * B + col));
    }
}

// ---------------------------------------------------------------------------
extern "C" void kernel_launch(void* const* d_in, const int* in_sizes, int n_in,
                              void* d_out, int out_size, void* d_ws, size_t ws_size,
                              hipStream_t stream) {
    const float* in = (const float*)d_in[0];   // [L, B]
    const float* U  = (const float*)d_in[1];   // [RANK, L]
    const float* V  = (const float*)d_in[2];   // [RANK, L]
    float* out = (float*)d_out;                // [L, B]

    // ws layout: partials (NCHUNK * RANK * B floats = 4 MiB) then T (RANK*B)
    float* part = (float*)d_ws;
    float* T    = part + (size_t)NCHUNK * RANK * B;

    lr_pass1 <<<CSTRIPE * NCHUNK,      256, 0, stream>>>(in, V, part);
    lr_reduce<<<(RANK * B) / (16 * 4), 256, 0, stream>>>(part, T);   // 512 blocks
    lr_pass2 <<<CB * (L / LPB),        256, 0, stream>>>(T, U, out);
}